// Round 11
// baseline (476.131 us; speedup 1.0000x reference)
//
#include <hip/hip_runtime.h>

// IntraClusterGAT on MI355X — Round 17: fused single kernel, manual grid
// barrier (R16's coop launch never ran: absmax == max|ref| => out stayed 0;
// hipLaunchCooperativeKernel validation rejected it. Sidestep the API).
//   Co-residency by construction: launch_bounds(256,4) + 38.4KB LDS + 64 VGPR
//   -> exactly 4 blocks/CU; grid 1024 = 4 x 256 CUs, all resident.
//   dispatch1: memset countv(0.8MB)+bar[3] (one small memset)
//   dispatch2: fused —
//     Phase A: zero accum (grid-stride) | threads<8192: Mtr/Pbf weights
//     Phase B: per-entry count -> countv (1 f32 atomic/thread)
//     Phase C: attn — R15-exact ping-pong 2-cluster pipeline (51.9µs proven)
//     Phase D: finalize — R12-exact MFMA + float4 LDS-transpose (782 blocks)
//   grid_bar: per-phase monotonic counter; ACQ_REL/ACQUIRE agent-scope
//   atomics emit wbl2/inv + vmcnt drain == kernel-boundary semantics.
// ws: accum[NN*64]bf16 | countv[NN]f32 | bar 256B | Mtr 4096bf16 | Pbf 4096bf16

#define NV 100000
#define NN 200000
#define NCLUST 2048
#define XS 72    // X/E row stride (bf16): 144B, 16B-aligned, conflict-free
#define GRIDN 1024

typedef __attribute__((ext_vector_type(8))) short short8;
typedef __attribute__((ext_vector_type(16))) float floatx16;
typedef __attribute__((ext_vector_type(4))) unsigned uint4v;

__device__ __forceinline__ unsigned short f2bf(float f) {
    union { float f; unsigned u; } v; v.f = f;
    unsigned r = v.u + 0x7fffu + ((v.u >> 16) & 1u);   // RNE
    return (unsigned short)(r >> 16);
}
__device__ __forceinline__ unsigned pack2bf(float lo, float hi) {
    union { float f; unsigned u; } a, b; a.f = lo; b.f = hi;
    unsigned ra = a.u + 0x7fffu + ((a.u >> 16) & 1u);
    unsigned rb = b.u + 0x7fffu + ((b.u >> 16) & 1u);
    return (ra >> 16) | (rb & 0xffff0000u);
}
__device__ __forceinline__ int crow(int r, int lane) {   // MFMA 32x32 C row map
    return (r & 3) + 8 * (r >> 2) + 4 * (lane >> 5);
}
// Barrier that orders LDS only (within-block phase steps of attn).
__device__ __forceinline__ void bar_lds() {
    __builtin_amdgcn_sched_barrier(0);
    asm volatile("s_waitcnt lgkmcnt(0)" ::: "memory");
    __builtin_amdgcn_s_barrier();
    __builtin_amdgcn_sched_barrier(0);
}
// Manual grid barrier: monotonic per-phase counter (zeroed by the memset).
// ACQ_REL add drains vmcnt + wbl2 (release of all prior global writes incl.
// fire-and-forget pk atomics); ACQUIRE spin-load invalidates L1/L2 so
// post-barrier plain loads refetch from the coherent point.
__device__ __forceinline__ void grid_bar(int* ctr) {
    __syncthreads();
    if (threadIdx.x == 0) {
        __hip_atomic_fetch_add(ctr, 1, __ATOMIC_ACQ_REL, __HIP_MEMORY_SCOPE_AGENT);
        int v;
        do {
            __builtin_amdgcn_s_sleep(2);
            v = __hip_atomic_load(ctr, __ATOMIC_ACQUIRE, __HIP_MEMORY_SCOPE_AGENT);
        } while (v < GRIDN);
    }
    __syncthreads();
}

struct SmemAttn {                         // 38400 B -> 4 blocks/CU
    unsigned short bufA[128 * XS];
    unsigned short bufB[128 * XS];
    int ids0[128], ids1[128];
    float bias0[64], bias1[64];
};
struct SmemFin {                          // 35840 B (aliases SmemAttn)
    float T[4][32][68];
    float cnts[256];
};

// ---- attn cluster compute (R15-exact, 51.9µs proven) ----
template<bool WN>
__device__ __forceinline__ void cluster_compute(
    unsigned short* X, unsigned short* E,
    const int* ids, const float* biascl,
    const unsigned short* __restrict__ Mtr,
    unsigned short* __restrict__ accum_bf,
    int lane, int w, int m, int hk, int r, int cb,
    short8 nx0, short8 nx1, short8 nx2, short8 nx3)
{
    // ---- GEMM1: Z = X @ M ----
    {
        floatx16 z0 = {}, z1 = {};
        #pragma unroll
        for (int ks = 0; ks < 4; ++ks) {
            short8 mb0 = *(const short8*)(Mtr + m * 64 + ks * 16 + hk);
            short8 mb1 = *(const short8*)(Mtr + (32 + m) * 64 + ks * 16 + hk);
            short8 a = *(const short8*)&X[(w * 32 + m) * XS + ks * 16 + hk];
            z0 = __builtin_amdgcn_mfma_f32_32x32x16_bf16(a, mb0, z0, 0, 0, 0);
            z1 = __builtin_amdgcn_mfma_f32_32x32x16_bf16(a, mb1, z1, 0, 0, 0);
        }
        #pragma unroll
        for (int rr = 0; rr < 16; ++rr) {
            int row = w * 32 + crow(rr, lane);
            E[row * XS + m]      = f2bf(z0[rr]);
            E[row * XS + 32 + m] = f2bf(z1[rr]);
        }
    }

    // ---- GEMM2: scores = Z @ X^T ----
    floatx16 sc[4] = {{}, {}, {}, {}};
    #pragma unroll
    for (int ks = 0; ks < 4; ++ks) {
        short8 a = *(const short8*)&E[(w * 32 + m) * XS + ks * 16 + hk];
        #pragma unroll
        for (int nt = 0; nt < 4; ++nt) {
            short8 b = *(const short8*)&X[(nt * 32 + m) * XS + ks * 16 + hk];
            sc[nt] = __builtin_amdgcn_mfma_f32_32x32x16_bf16(a, b, sc[nt], 0, 0, 0);
        }
    }

    // ---- bias + leaky_relu + exp + rowsum(shfl) + normalize ----
    const float b2 = biascl[m], b3 = biascl[32 + m];
    #pragma unroll
    for (int rr = 0; rr < 16; ++rr) {
        float a0 = sc[0][rr], a1 = sc[1][rr], a2 = sc[2][rr] + b2, a3 = sc[3][rr] + b3;
        a0 = a0 > 0.f ? a0 : 0.2f * a0;
        a1 = a1 > 0.f ? a1 : 0.2f * a1;
        a2 = a2 > 0.f ? a2 : 0.2f * a2;
        a3 = a3 > 0.f ? a3 : 0.2f * a3;
        a0 = __expf(a0); a1 = __expf(a1); a2 = __expf(a2); a3 = __expf(a3);
        float s4 = (a0 + a1) + (a2 + a3);
        #pragma unroll
        for (int off = 1; off < 32; off <<= 1) s4 += __shfl_xor(s4, off, 64);
        float inv = __builtin_amdgcn_rcpf(s4);
        sc[0][rr] = a0 * inv; sc[1][rr] = a1 * inv;
        sc[2][rr] = a2 * inv; sc[3][rr] = a3 * inv;
    }

    // ---- E-half 1 ----
    #pragma unroll
    for (int rr = 0; rr < 16; ++rr) {
        int row = w * 32 + crow(rr, lane);
        E[row * XS + m]      = f2bf(sc[0][rr]);
        E[row * XS + 32 + m] = f2bf(sc[1][rr]);
    }

    // ---- GEMM3 half 1 ----
    floatx16 g0 = {}, g1 = {};
    #pragma unroll
    for (int ks = 0; ks < 4; ++ks) {
        short8 a = *(const short8*)&E[(w * 32 + m) * XS + ks * 16 + hk];
        short8 b0, b1;
        #pragma unroll
        for (int j = 0; j < 8; ++j) {
            int t = ks * 16 + hk + j;
            b0[j] = (short)X[t * XS + m];
            b1[j] = (short)X[t * XS + 32 + m];
        }
        g0 = __builtin_amdgcn_mfma_f32_32x32x16_bf16(a, b0, g0, 0, 0, 0);
        g1 = __builtin_amdgcn_mfma_f32_32x32x16_bf16(a, b1, g1, 0, 0, 0);
    }

    // ---- E-half 2 ----
    #pragma unroll
    for (int rr = 0; rr < 16; ++rr) {
        int row = w * 32 + crow(rr, lane);
        E[row * XS + m]      = f2bf(sc[2][rr]);
        E[row * XS + 32 + m] = f2bf(sc[3][rr]);
    }

    // ---- GEMM3 half 2 ----
    #pragma unroll
    for (int ks = 0; ks < 4; ++ks) {
        short8 a = *(const short8*)&E[(w * 32 + m) * XS + ks * 16 + hk];
        short8 b0, b1;
        #pragma unroll
        for (int j = 0; j < 8; ++j) {
            int t = 64 + ks * 16 + hk + j;
            b0[j] = (short)X[t * XS + m];
            b1[j] = (short)X[t * XS + 32 + m];
        }
        g0 = __builtin_amdgcn_mfma_f32_32x32x16_bf16(a, b0, g0, 0, 0, 0);
        g1 = __builtin_amdgcn_mfma_f32_32x32x16_bf16(a, b1, g1, 0, 0, 0);
    }

    // ---- park next cluster's X rows into E ----
    if (WN) {
        *(short8*)&E[r * XS + cb +  0] = nx0;
        *(short8*)&E[r * XS + cb +  8] = nx1;
        *(short8*)&E[r * XS + cb + 16] = nx2;
        *(short8*)&E[r * XS + cb + 24] = nx3;
    }

    // ---- pack adjacent cols + pk_add_bf16 scatter ----
    const bool ev = !(lane & 1);
    const int colbase = ev ? m : (31 + m);
    #pragma unroll
    for (int rr = 0; rr < 16; ++rr) {
        int row = w * 32 + crow(rr, lane);
        int nid = ids[row];
        float a0 = g0[rr], a1 = g1[rr];
        float t0 = __shfl_xor(a0, 1, 64);
        float t1 = __shfl_xor(a1, 1, 64);
        float lo = ev ? a0 : t1;
        float hi = ev ? t0 : a1;
        unsigned pk = (unsigned)f2bf(lo) | ((unsigned)f2bf(hi) << 16);
        unsigned long long addr =
            (unsigned long long)(accum_bf + (size_t)nid * 64 + colbase);
        asm volatile("global_atomic_pk_add_bf16 %0, %1, off"
                     :: "v"(addr), "v"(pk) : "memory");
    }
}

extern "C" __global__ __launch_bounds__(256, 4) void fused_kernel(
    const float* __restrict__ x_var, const float* __restrict__ x_clause,
    const int* __restrict__ cvar, const int* __restrict__ ccl,
    const float* __restrict__ sat,
    const float* __restrict__ WQ, const float* __restrict__ WK,
    const float* __restrict__ WV, const float* __restrict__ Wout,
    const float* __restrict__ head_weights, const int* __restrict__ active_heads_p,
    const float* __restrict__ bout,
    unsigned short* __restrict__ accum_bf, float* __restrict__ countv,
    int* __restrict__ barp,
    unsigned short* __restrict__ Mtr, unsigned short* __restrict__ Pbf,
    float* __restrict__ out)
{
    __shared__ __align__(16) char smem_raw[sizeof(SmemAttn)];   // 38400 B

    const int tid = threadIdx.x, bid = blockIdx.x;
    const int gthread = bid * 256 + tid;                         // 0..262143
    const int lane = tid & 63, w = tid >> 6;
    const int m = lane & 31, hk = (lane >> 5) * 8;

    // ================= Phase A: zero accum; weights ========================
    {
        uint4v z = {0u, 0u, 0u, 0u};
        uint4v* zb = (uint4v*)accum_bf;              // accum only (25.6MB)
        for (int j = gthread; j < 1600000; j += 262144) zb[j] = z;
        int o = gthread;
        if (o < 4096) {
            int d = o >> 6, a = o & 63;                  // Mtr[d][a] = M[a][d]
            float acc = 0.f;
            for (int j = 0; j < 64; ++j) acc += WQ[j*64 + a] * WK[j*64 + d];
            Mtr[o] = f2bf(acc * 0.125f);
        } else if (o < 8192) {
            int ah = active_heads_p[0];
            float hw = 0.f;
            for (int i = 0; i < ah; ++i) hw += head_weights[i];
            hw /= (float)ah;
            int o2 = o - 4096;
            int j = o2 >> 6, b = o2 & 63;                // Pbf[j][b]
            float acc = 0.f;
            for (int d = 0; d < 64; ++d) acc += Wout[j*64 + d] * WV[d*64 + b];
            Pbf[o2] = f2bf(acc * hw);
        }
    }
    grid_bar(&barp[0]);

    // ================= Phase B: per-entry counting =========================
    {
        int c = gthread >> 7, r = gthread & 127;
        int nid = (r < 64) ? cvar[c * 64 + r] : (NV + ccl[c * 64 + (r - 64)]);
        atomicAdd(&countv[nid], 1.0f);
    }
    grid_bar(&barp[16]);

    // ================= Phase C: attn (R15-exact) ===========================
    {
        SmemAttn* S = (SmemAttn*)smem_raw;
        const int c0 = bid * 2;
        const int r = tid >> 1, half = tid & 1, cb = half * 32;

        int nid0, nid1;
        const float *src0, *src1;
        float sv0 = 0.f, sv1 = 0.f;
        if (r < 64) {
            nid0 = cvar[c0 * 64 + r];
            nid1 = cvar[c0 * 64 + 64 + r];
            src0 = x_var + (size_t)nid0 * 64;
            src1 = x_var + (size_t)nid1 * 64;
        } else {
            int cid0 = ccl[c0 * 64 + (r - 64)];
            int cid1 = ccl[c0 * 64 + r];
            nid0 = NV + cid0; nid1 = NV + cid1;
            src0 = x_clause + (size_t)cid0 * 64;
            src1 = x_clause + (size_t)cid1 * 64;
            if (half) { sv0 = sat[cid0]; sv1 = sat[cid1]; }
        }

        const float4* s40 = (const float4*)src0 + half * 8;
        const float4* s41 = (const float4*)src1 + half * 8;
        float4 v0[8], v1[8];
        #pragma unroll
        for (int i = 0; i < 8; ++i) v0[i] = s40[i];
        #pragma unroll
        for (int i = 0; i < 8; ++i) v1[i] = s41[i];

        if (!half) { S->ids0[r] = nid0; S->ids1[r] = nid1; }
        if (r >= 64 && half) { S->bias0[r - 64] = sv0; S->bias1[r - 64] = sv1; }

        {
            union { unsigned u[16]; short8 v[4]; } h0;
            #pragma unroll
            for (int i = 0; i < 8; ++i) {
                h0.u[2*i]   = pack2bf(v0[i].x, v0[i].y);
                h0.u[2*i+1] = pack2bf(v0[i].z, v0[i].w);
            }
            #pragma unroll
            for (int i = 0; i < 4; ++i)
                *(short8*)&S->bufA[r * XS + cb + i * 8] = h0.v[i];
        }
        union { unsigned u[16]; short8 v[4]; } h1;
        #pragma unroll
        for (int i = 0; i < 8; ++i) {
            h1.u[2*i]   = pack2bf(v1[i].x, v1[i].y);
            h1.u[2*i+1] = pack2bf(v1[i].z, v1[i].w);
        }

        bar_lds();   // bufA + ids visible

        cluster_compute<true>(S->bufA, S->bufB, S->ids0, S->bias0, Mtr, accum_bf,
                              lane, w, m, hk, r, cb,
                              h1.v[0], h1.v[1], h1.v[2], h1.v[3]);

        bar_lds();   // bufA/bufB(c0) reads done; c1 X now in bufB.

        short8 zz = {};
        cluster_compute<false>(S->bufB, S->bufA, S->ids1, S->bias1, Mtr, accum_bf,
                               lane, w, m, hk, r, cb, zz, zz, zz, zz);
    }
    grid_bar(&barp[32]);   // release drains pk atomics; acquire invalidates

    // ================= Phase D: finalize (R12-exact) =======================
    if (bid < (NN + 255) / 256) {
        SmemFin* F = (SmemFin*)smem_raw;
        const int base = bid * 256;
        {
            int n = base + tid;
            F->cnts[tid] = (n < NN) ? countv[n] : 1.f;
        }
        __syncthreads();

        short8 pb[2][4];
        #pragma unroll
        for (int nt = 0; nt < 2; ++nt)
            #pragma unroll
            for (int ks = 0; ks < 4; ++ks)
                pb[nt][ks] = *(const short8*)(Pbf + (nt * 32 + m) * 64 + ks * 16 + hk);
        const float bias0 = bout[m], bias1 = bout[32 + m];

        const int r2 = lane >> 1, cb2 = (lane & 1) * 32;

        #pragma unroll
        for (int tm = 0; tm < 2; ++tm) {
            int mt = w * 2 + tm;
            const unsigned short* arow = accum_bf + (size_t)(base + mt * 32 + m) * 64;
            floatx16 c0 = {}, c1 = {};
            #pragma unroll
            for (int ks = 0; ks < 4; ++ks) {
                short8 a = *(const short8*)(arow + ks * 16 + hk);
                c0 = __builtin_amdgcn_mfma_f32_32x32x16_bf16(a, pb[0][ks], c0, 0, 0, 0);
                c1 = __builtin_amdgcn_mfma_f32_32x32x16_bf16(a, pb[1][ks], c1, 0, 0, 0);
            }
            #pragma unroll
            for (int rr = 0; rr < 16; ++rr) {
                int lr32 = crow(rr, lane);
                float inv = 1.0f / fmaxf(F->cnts[mt * 32 + lr32], 1.0f);
                F->T[w][lr32][m]      = c0[rr] * inv + bias0;
                F->T[w][lr32][32 + m] = c1[rr] * inv + bias1;
            }
            // wave-local DS in-order: reads below see this wave's writes.
            int n2 = base + mt * 32 + r2;
            if (n2 < NN) {
                const float* xr = (n2 < NV) ? (x_var + (size_t)n2 * 64)
                                            : (x_clause + (size_t)(n2 - NV) * 64);
                float* orow = out + (size_t)n2 * 64;
                #pragma unroll
                for (int j = 0; j < 8; ++j) {
                    float4 t = *(const float4*)&F->T[w][r2][cb2 + 4 * j];
                    float4 xv = *(const float4*)&xr[cb2 + 4 * j];
                    float4 o;
                    o.x = t.x + xv.x; o.y = t.y + xv.y;
                    o.z = t.z + xv.z; o.w = t.w + xv.w;
                    *(float4*)&orow[cb2 + 4 * j] = o;
                }
            }
        }
    }
}

extern "C" void kernel_launch(void* const* d_in, const int* in_sizes, int n_in,
                              void* d_out, int out_size, void* d_ws, size_t ws_size,
                              hipStream_t stream)
{
    const float* x_var        = (const float*)d_in[0];
    const float* x_clause     = (const float*)d_in[1];
    const int*   cvar         = (const int*)d_in[4];
    const int*   ccl          = (const int*)d_in[5];
    const float* sat          = (const float*)d_in[6];
    const int*   active_heads = (const int*)d_in[7];
    const float* WQ           = (const float*)d_in[8];
    const float* WK           = (const float*)d_in[9];
    const float* WV           = (const float*)d_in[10];
    const float* head_weights = (const float*)d_in[11];
    const float* Wout         = (const float*)d_in[12];
    const float* bout         = (const float*)d_in[13];

    unsigned short* accum_bf = (unsigned short*)d_ws;          // NN*64 bf16
    float* countv = (float*)(accum_bf + (size_t)NN * 64);      // NN f32
    int* barp = (int*)(countv + NN);                           // 256 B barriers
    unsigned short* Mtr = (unsigned short*)(barp + 64);        // 4096 bf16
    unsigned short* Pbf = Mtr + 4096;                          // 4096 bf16

    // one small memset: countv (0.8MB) + barrier counters (256B), contiguous
    hipMemsetAsync(countv, 0, (size_t)NN * 4 + 256, stream);
    fused_kernel<<<GRIDN, 256, 0, stream>>>(
        x_var, x_clause, cvar, ccl, sat, WQ, WK, WV, Wout, head_weights,
        active_heads, bout, accum_bf, countv, barp, Mtr, Pbf, (float*)d_out);
}

// Round 12
// 401.748 us; speedup vs baseline: 1.1851x; 1.1851x over previous
//
#include <hip/hip_runtime.h>

// IntraClusterGAT on MI355X — Round 18: fused kernel, fixed grid barrier.
//   R17 diagnosis: ACQUIRE spin-load = L1/L2 invalidate every ~128cy per
//   waiting block -> cache-invalidate storm while late blocks run attn ->
//   730 GB/s latency-bound crawl (300µs). Fix: spin RELAXED (agent-scope
//   atomic load reads coherent point, NO invalidate), single ACQUIRE after
//   exit (one invalidate per block per barrier). Also phases A,B merged ->
//   2 grid barriers.
//   dispatch1: memset countv(0.8MB)+bar (one small memset)
//   dispatch2: fused —
//     Phase A: zero accum | Mtr/Pbf weights | per-entry count -> countv
//     Phase C: attn — R15-exact ping-pong 2-cluster pipeline (51.9µs proven)
//     Phase D: finalize — R12-exact MFMA + float4 LDS-transpose (782 blocks)
//   Co-residency by construction: launch_bounds(256,4) + 38.4KB LDS + 64
//   VGPR -> 4 blocks/CU; grid 1024 = 4 x 256 CUs, all resident.
// ws: accum[NN*64]bf16 | countv[NN]f32 | bar 256B | Mtr 4096bf16 | Pbf 4096bf16

#define NV 100000
#define NN 200000
#define NCLUST 2048
#define XS 72    // X/E row stride (bf16): 144B, 16B-aligned, conflict-free
#define GRIDN 1024

typedef __attribute__((ext_vector_type(8))) short short8;
typedef __attribute__((ext_vector_type(16))) float floatx16;
typedef __attribute__((ext_vector_type(4))) unsigned uint4v;

__device__ __forceinline__ unsigned short f2bf(float f) {
    union { float f; unsigned u; } v; v.f = f;
    unsigned r = v.u + 0x7fffu + ((v.u >> 16) & 1u);   // RNE
    return (unsigned short)(r >> 16);
}
__device__ __forceinline__ unsigned pack2bf(float lo, float hi) {
    union { float f; unsigned u; } a, b; a.f = lo; b.f = hi;
    unsigned ra = a.u + 0x7fffu + ((a.u >> 16) & 1u);
    unsigned rb = b.u + 0x7fffu + ((b.u >> 16) & 1u);
    return (ra >> 16) | (rb & 0xffff0000u);
}
__device__ __forceinline__ int crow(int r, int lane) {   // MFMA 32x32 C row map
    return (r & 3) + 8 * (r >> 2) + 4 * (lane >> 5);
}
// Barrier that orders LDS only (within-block phase steps of attn).
__device__ __forceinline__ void bar_lds() {
    __builtin_amdgcn_sched_barrier(0);
    asm volatile("s_waitcnt lgkmcnt(0)" ::: "memory");
    __builtin_amdgcn_s_barrier();
    __builtin_amdgcn_sched_barrier(0);
}
// Manual grid barrier (fixed): release fetch_add; RELAXED spin (agent-scope
// atomic load reads the memory-side coherent point, no cache invalidate);
// ONE acquire load after exit (single L1/L2 invalidate per block/barrier).
__device__ __forceinline__ void grid_bar(int* ctr) {
    __syncthreads();   // per-wave vmcnt drain + block converge
    if (threadIdx.x == 0) {
        __hip_atomic_fetch_add(ctr, 1, __ATOMIC_ACQ_REL, __HIP_MEMORY_SCOPE_AGENT);
        int v;
        do {
            __builtin_amdgcn_s_sleep(16);   // ~1k cycles between probes
            v = __hip_atomic_load(ctr, __ATOMIC_RELAXED, __HIP_MEMORY_SCOPE_AGENT);
        } while (v < GRIDN);
        (void)__hip_atomic_load(ctr, __ATOMIC_ACQUIRE, __HIP_MEMORY_SCOPE_AGENT);
    }
    __syncthreads();
}

struct SmemAttn {                         // 38400 B -> 4 blocks/CU
    unsigned short bufA[128 * XS];
    unsigned short bufB[128 * XS];
    int ids0[128], ids1[128];
    float bias0[64], bias1[64];
};
struct SmemFin {                          // 35840 B (aliases SmemAttn)
    float T[4][32][68];
    float cnts[256];
};

// ---- attn cluster compute (R15-exact, 51.9µs proven) ----
template<bool WN>
__device__ __forceinline__ void cluster_compute(
    unsigned short* X, unsigned short* E,
    const int* ids, const float* biascl,
    const unsigned short* __restrict__ Mtr,
    unsigned short* __restrict__ accum_bf,
    int lane, int w, int m, int hk, int r, int cb,
    short8 nx0, short8 nx1, short8 nx2, short8 nx3)
{
    // ---- GEMM1: Z = X @ M ----
    {
        floatx16 z0 = {}, z1 = {};
        #pragma unroll
        for (int ks = 0; ks < 4; ++ks) {
            short8 mb0 = *(const short8*)(Mtr + m * 64 + ks * 16 + hk);
            short8 mb1 = *(const short8*)(Mtr + (32 + m) * 64 + ks * 16 + hk);
            short8 a = *(const short8*)&X[(w * 32 + m) * XS + ks * 16 + hk];
            z0 = __builtin_amdgcn_mfma_f32_32x32x16_bf16(a, mb0, z0, 0, 0, 0);
            z1 = __builtin_amdgcn_mfma_f32_32x32x16_bf16(a, mb1, z1, 0, 0, 0);
        }
        #pragma unroll
        for (int rr = 0; rr < 16; ++rr) {
            int row = w * 32 + crow(rr, lane);
            E[row * XS + m]      = f2bf(z0[rr]);
            E[row * XS + 32 + m] = f2bf(z1[rr]);
        }
    }

    // ---- GEMM2: scores = Z @ X^T ----
    floatx16 sc[4] = {{}, {}, {}, {}};
    #pragma unroll
    for (int ks = 0; ks < 4; ++ks) {
        short8 a = *(const short8*)&E[(w * 32 + m) * XS + ks * 16 + hk];
        #pragma unroll
        for (int nt = 0; nt < 4; ++nt) {
            short8 b = *(const short8*)&X[(nt * 32 + m) * XS + ks * 16 + hk];
            sc[nt] = __builtin_amdgcn_mfma_f32_32x32x16_bf16(a, b, sc[nt], 0, 0, 0);
        }
    }

    // ---- bias + leaky_relu + exp + rowsum(shfl) + normalize ----
    const float b2 = biascl[m], b3 = biascl[32 + m];
    #pragma unroll
    for (int rr = 0; rr < 16; ++rr) {
        float a0 = sc[0][rr], a1 = sc[1][rr], a2 = sc[2][rr] + b2, a3 = sc[3][rr] + b3;
        a0 = a0 > 0.f ? a0 : 0.2f * a0;
        a1 = a1 > 0.f ? a1 : 0.2f * a1;
        a2 = a2 > 0.f ? a2 : 0.2f * a2;
        a3 = a3 > 0.f ? a3 : 0.2f * a3;
        a0 = __expf(a0); a1 = __expf(a1); a2 = __expf(a2); a3 = __expf(a3);
        float s4 = (a0 + a1) + (a2 + a3);
        #pragma unroll
        for (int off = 1; off < 32; off <<= 1) s4 += __shfl_xor(s4, off, 64);
        float inv = __builtin_amdgcn_rcpf(s4);
        sc[0][rr] = a0 * inv; sc[1][rr] = a1 * inv;
        sc[2][rr] = a2 * inv; sc[3][rr] = a3 * inv;
    }

    // ---- E-half 1 ----
    #pragma unroll
    for (int rr = 0; rr < 16; ++rr) {
        int row = w * 32 + crow(rr, lane);
        E[row * XS + m]      = f2bf(sc[0][rr]);
        E[row * XS + 32 + m] = f2bf(sc[1][rr]);
    }

    // ---- GEMM3 half 1 ----
    floatx16 g0 = {}, g1 = {};
    #pragma unroll
    for (int ks = 0; ks < 4; ++ks) {
        short8 a = *(const short8*)&E[(w * 32 + m) * XS + ks * 16 + hk];
        short8 b0, b1;
        #pragma unroll
        for (int j = 0; j < 8; ++j) {
            int t = ks * 16 + hk + j;
            b0[j] = (short)X[t * XS + m];
            b1[j] = (short)X[t * XS + 32 + m];
        }
        g0 = __builtin_amdgcn_mfma_f32_32x32x16_bf16(a, b0, g0, 0, 0, 0);
        g1 = __builtin_amdgcn_mfma_f32_32x32x16_bf16(a, b1, g1, 0, 0, 0);
    }

    // ---- E-half 2 ----
    #pragma unroll
    for (int rr = 0; rr < 16; ++rr) {
        int row = w * 32 + crow(rr, lane);
        E[row * XS + m]      = f2bf(sc[2][rr]);
        E[row * XS + 32 + m] = f2bf(sc[3][rr]);
    }

    // ---- GEMM3 half 2 ----
    #pragma unroll
    for (int ks = 0; ks < 4; ++ks) {
        short8 a = *(const short8*)&E[(w * 32 + m) * XS + ks * 16 + hk];
        short8 b0, b1;
        #pragma unroll
        for (int j = 0; j < 8; ++j) {
            int t = 64 + ks * 16 + hk + j;
            b0[j] = (short)X[t * XS + m];
            b1[j] = (short)X[t * XS + 32 + m];
        }
        g0 = __builtin_amdgcn_mfma_f32_32x32x16_bf16(a, b0, g0, 0, 0, 0);
        g1 = __builtin_amdgcn_mfma_f32_32x32x16_bf16(a, b1, g1, 0, 0, 0);
    }

    // ---- park next cluster's X rows into E ----
    if (WN) {
        *(short8*)&E[r * XS + cb +  0] = nx0;
        *(short8*)&E[r * XS + cb +  8] = nx1;
        *(short8*)&E[r * XS + cb + 16] = nx2;
        *(short8*)&E[r * XS + cb + 24] = nx3;
    }

    // ---- pack adjacent cols + pk_add_bf16 scatter ----
    const bool ev = !(lane & 1);
    const int colbase = ev ? m : (31 + m);
    #pragma unroll
    for (int rr = 0; rr < 16; ++rr) {
        int row = w * 32 + crow(rr, lane);
        int nid = ids[row];
        float a0 = g0[rr], a1 = g1[rr];
        float t0 = __shfl_xor(a0, 1, 64);
        float t1 = __shfl_xor(a1, 1, 64);
        float lo = ev ? a0 : t1;
        float hi = ev ? t0 : a1;
        unsigned pk = (unsigned)f2bf(lo) | ((unsigned)f2bf(hi) << 16);
        unsigned long long addr =
            (unsigned long long)(accum_bf + (size_t)nid * 64 + colbase);
        asm volatile("global_atomic_pk_add_bf16 %0, %1, off"
                     :: "v"(addr), "v"(pk) : "memory");
    }
}

extern "C" __global__ __launch_bounds__(256, 4) void fused_kernel(
    const float* __restrict__ x_var, const float* __restrict__ x_clause,
    const int* __restrict__ cvar, const int* __restrict__ ccl,
    const float* __restrict__ sat,
    const float* __restrict__ WQ, const float* __restrict__ WK,
    const float* __restrict__ WV, const float* __restrict__ Wout,
    const float* __restrict__ head_weights, const int* __restrict__ active_heads_p,
    const float* __restrict__ bout,
    unsigned short* __restrict__ accum_bf, float* __restrict__ countv,
    int* __restrict__ barp,
    unsigned short* __restrict__ Mtr, unsigned short* __restrict__ Pbf,
    float* __restrict__ out)
{
    __shared__ __align__(16) char smem_raw[sizeof(SmemAttn)];   // 38400 B

    const int tid = threadIdx.x, bid = blockIdx.x;
    const int gthread = bid * 256 + tid;                         // 0..262143
    const int lane = tid & 63, w = tid >> 6;
    const int m = lane & 31, hk = (lane >> 5) * 8;

    // ========= Phase A: zero accum | weights | per-entry counting =========
    {
        uint4v z = {0u, 0u, 0u, 0u};
        uint4v* zb = (uint4v*)accum_bf;              // accum only (25.6MB)
        for (int j = gthread; j < 1600000; j += 262144) zb[j] = z;
        int o = gthread;
        if (o < 4096) {
            int d = o >> 6, a = o & 63;                  // Mtr[d][a] = M[a][d]
            float acc = 0.f;
            for (int j = 0; j < 64; ++j) acc += WQ[j*64 + a] * WK[j*64 + d];
            Mtr[o] = f2bf(acc * 0.125f);
        } else if (o < 8192) {
            int ah = active_heads_p[0];
            float hw = 0.f;
            for (int i = 0; i < ah; ++i) hw += head_weights[i];
            hw /= (float)ah;
            int o2 = o - 4096;
            int j = o2 >> 6, b = o2 & 63;                // Pbf[j][b]
            float acc = 0.f;
            for (int d = 0; d < 64; ++d) acc += Wout[j*64 + d] * WV[d*64 + b];
            Pbf[o2] = f2bf(acc * hw);
        }
        // per-entry counting (countv zeroed by the host-side memset;
        // independent of the accum zeroing above)
        int c = gthread >> 7, rr = gthread & 127;
        int nid = (rr < 64) ? cvar[c * 64 + rr] : (NV + ccl[c * 64 + (rr - 64)]);
        atomicAdd(&countv[nid], 1.0f);
    }
    grid_bar(&barp[0]);

    // ================= Phase C: attn (R15-exact) ===========================
    {
        SmemAttn* S = (SmemAttn*)smem_raw;
        const int c0 = bid * 2;
        const int r = tid >> 1, half = tid & 1, cb = half * 32;

        int nid0, nid1;
        const float *src0, *src1;
        float sv0 = 0.f, sv1 = 0.f;
        if (r < 64) {
            nid0 = cvar[c0 * 64 + r];
            nid1 = cvar[c0 * 64 + 64 + r];
            src0 = x_var + (size_t)nid0 * 64;
            src1 = x_var + (size_t)nid1 * 64;
        } else {
            int cid0 = ccl[c0 * 64 + (r - 64)];
            int cid1 = ccl[c0 * 64 + r];
            nid0 = NV + cid0; nid1 = NV + cid1;
            src0 = x_clause + (size_t)cid0 * 64;
            src1 = x_clause + (size_t)cid1 * 64;
            if (half) { sv0 = sat[cid0]; sv1 = sat[cid1]; }
        }

        const float4* s40 = (const float4*)src0 + half * 8;
        const float4* s41 = (const float4*)src1 + half * 8;
        float4 v0[8], v1[8];
        #pragma unroll
        for (int i = 0; i < 8; ++i) v0[i] = s40[i];
        #pragma unroll
        for (int i = 0; i < 8; ++i) v1[i] = s41[i];

        if (!half) { S->ids0[r] = nid0; S->ids1[r] = nid1; }
        if (r >= 64 && half) { S->bias0[r - 64] = sv0; S->bias1[r - 64] = sv1; }

        {
            union { unsigned u[16]; short8 v[4]; } h0;
            #pragma unroll
            for (int i = 0; i < 8; ++i) {
                h0.u[2*i]   = pack2bf(v0[i].x, v0[i].y);
                h0.u[2*i+1] = pack2bf(v0[i].z, v0[i].w);
            }
            #pragma unroll
            for (int i = 0; i < 4; ++i)
                *(short8*)&S->bufA[r * XS + cb + i * 8] = h0.v[i];
        }
        union { unsigned u[16]; short8 v[4]; } h1;
        #pragma unroll
        for (int i = 0; i < 8; ++i) {
            h1.u[2*i]   = pack2bf(v1[i].x, v1[i].y);
            h1.u[2*i+1] = pack2bf(v1[i].z, v1[i].w);
        }

        bar_lds();   // bufA + ids visible

        cluster_compute<true>(S->bufA, S->bufB, S->ids0, S->bias0, Mtr, accum_bf,
                              lane, w, m, hk, r, cb,
                              h1.v[0], h1.v[1], h1.v[2], h1.v[3]);

        bar_lds();   // bufA/bufB(c0) reads done; c1 X now in bufB.

        short8 zz = {};
        cluster_compute<false>(S->bufB, S->bufA, S->ids1, S->bias1, Mtr, accum_bf,
                               lane, w, m, hk, r, cb, zz, zz, zz, zz);
    }
    grid_bar(&barp[32]);   // release drains pk atomics; one acquire inv

    // ================= Phase D: finalize (R12-exact) =======================
    if (bid < (NN + 255) / 256) {
        SmemFin* F = (SmemFin*)smem_raw;
        const int base = bid * 256;
        {
            int n = base + tid;
            F->cnts[tid] = (n < NN) ? countv[n] : 1.f;
        }
        __syncthreads();

        short8 pb[2][4];
        #pragma unroll
        for (int nt = 0; nt < 2; ++nt)
            #pragma unroll
            for (int ks = 0; ks < 4; ++ks)
                pb[nt][ks] = *(const short8*)(Pbf + (nt * 32 + m) * 64 + ks * 16 + hk);
        const float bias0 = bout[m], bias1 = bout[32 + m];

        const int r2 = lane >> 1, cb2 = (lane & 1) * 32;

        #pragma unroll
        for (int tm = 0; tm < 2; ++tm) {
            int mt = w * 2 + tm;
            const unsigned short* arow = accum_bf + (size_t)(base + mt * 32 + m) * 64;
            floatx16 c0 = {}, c1 = {};
            #pragma unroll
            for (int ks = 0; ks < 4; ++ks) {
                short8 a = *(const short8*)(arow + ks * 16 + hk);
                c0 = __builtin_amdgcn_mfma_f32_32x32x16_bf16(a, pb[0][ks], c0, 0, 0, 0);
                c1 = __builtin_amdgcn_mfma_f32_32x32x16_bf16(a, pb[1][ks], c1, 0, 0, 0);
            }
            #pragma unroll
            for (int rr = 0; rr < 16; ++rr) {
                int lr32 = crow(rr, lane);
                float inv = 1.0f / fmaxf(F->cnts[mt * 32 + lr32], 1.0f);
                F->T[w][lr32][m]      = c0[rr] * inv + bias0;
                F->T[w][lr32][32 + m] = c1[rr] * inv + bias1;
            }
            // wave-local DS in-order: reads below see this wave's writes.
            int n2 = base + mt * 32 + r2;
            if (n2 < NN) {
                const float* xr = (n2 < NV) ? (x_var + (size_t)n2 * 64)
                                            : (x_clause + (size_t)(n2 - NV) * 64);
                float* orow = out + (size_t)n2 * 64;
                #pragma unroll
                for (int j = 0; j < 8; ++j) {
                    float4 t = *(const float4*)&F->T[w][r2][cb2 + 4 * j];
                    float4 xv = *(const float4*)&xr[cb2 + 4 * j];
                    float4 o;
                    o.x = t.x + xv.x; o.y = t.y + xv.y;
                    o.z = t.z + xv.z; o.w = t.w + xv.w;
                    *(float4*)&orow[cb2 + 4 * j] = o;
                }
            }
        }
    }
}

extern "C" void kernel_launch(void* const* d_in, const int* in_sizes, int n_in,
                              void* d_out, int out_size, void* d_ws, size_t ws_size,
                              hipStream_t stream)
{
    const float* x_var        = (const float*)d_in[0];
    const float* x_clause     = (const float*)d_in[1];
    const int*   cvar         = (const int*)d_in[4];
    const int*   ccl          = (const int*)d_in[5];
    const float* sat          = (const float*)d_in[6];
    const int*   active_heads = (const int*)d_in[7];
    const float* WQ           = (const float*)d_in[8];
    const float* WK           = (const float*)d_in[9];
    const float* WV           = (const float*)d_in[10];
    const float* head_weights = (const float*)d_in[11];
    const float* Wout         = (const float*)d_in[12];
    const float* bout         = (const float*)d_in[13];

    unsigned short* accum_bf = (unsigned short*)d_ws;          // NN*64 bf16
    float* countv = (float*)(accum_bf + (size_t)NN * 64);      // NN f32
    int* barp = (int*)(countv + NN);                           // 256 B barriers
    unsigned short* Mtr = (unsigned short*)(barp + 64);        // 4096 bf16
    unsigned short* Pbf = Mtr + 4096;                          // 4096 bf16

    // one small memset: countv (0.8MB) + barrier counters (256B), contiguous
    hipMemsetAsync(countv, 0, (size_t)NN * 4 + 256, stream);
    fused_kernel<<<GRIDN, 256, 0, stream>>>(
        x_var, x_clause, cvar, ccl, sat, WQ, WK, WV, Wout, head_weights,
        active_heads, bout, accum_bf, countv, barp, Mtr, Pbf, (float*)d_out);
}

// Round 13
// 213.613 us; speedup vs baseline: 2.2289x; 1.8807x over previous
//
#include <hip/hip_runtime.h>

// IntraClusterGAT on MI355X — Round 19: R12 revert (best, 209.7µs) + one
// placement change: countv atomicAdds moved from attn's startup (where they
// contend with the critical-path x-row gathers) to the kernel tail (where
// they join the fire-and-forget scatter drain). R15 proved the startup
// counts cost ~6µs; this captures that without R15's extra dispatch.
//   prep:  Mtr/Pbf weights + grid-stride zeroing of accum_bf/countv
//   attn:  R8/R12 ping-pong 2-cluster pipeline; counts issued at kernel end
//   final: R12 MFMA + float4 LDS-transpose epilogue
// 3 dispatches (minimum: prep is the zeroing pass; attn->finalize has a hard
// global dependency through the scattered atomics).
// ws: accum_bf[NN*64] bf16 | countv[NN] f32 | Mtr 4096 bf16 | Pbf 4096 bf16

#define NV 100000
#define NN 200000
#define NCLUST 2048
#define XS 72    // X/E row stride (bf16): 144B, 16B-aligned, conflict-free

typedef __attribute__((ext_vector_type(8))) short short8;
typedef __attribute__((ext_vector_type(16))) float floatx16;
typedef __attribute__((ext_vector_type(4))) unsigned uint4v;

__device__ __forceinline__ unsigned short f2bf(float f) {
    union { float f; unsigned u; } v; v.f = f;
    unsigned r = v.u + 0x7fffu + ((v.u >> 16) & 1u);   // RNE
    return (unsigned short)(r >> 16);
}
__device__ __forceinline__ unsigned pack2bf(float lo, float hi) {
    union { float f; unsigned u; } a, b; a.f = lo; b.f = hi;
    unsigned ra = a.u + 0x7fffu + ((a.u >> 16) & 1u);
    unsigned rb = b.u + 0x7fffu + ((b.u >> 16) & 1u);
    return (ra >> 16) | (rb & 0xffff0000u);
}
__device__ __forceinline__ int crow(int r, int lane) {   // MFMA 32x32 C row map
    return (r & 3) + 8 * (r >> 2) + 4 * (lane >> 5);
}
// Barrier that orders LDS only: waves drain their own DS ops, then s_barrier.
// Global atomics (accum scatter, countv) intentionally stay in flight.
__device__ __forceinline__ void bar_lds() {
    __builtin_amdgcn_sched_barrier(0);
    asm volatile("s_waitcnt lgkmcnt(0)" ::: "memory");
    __builtin_amdgcn_s_barrier();
    __builtin_amdgcn_sched_barrier(0);
}

// ---- prep: Mtr/Pbf weights + zero accum_bf/countv (replaces memset) ----
#define ZU4 1650000   // (NN*64*2 + NN*4) / 16 bytes -> uint4 count
__global__ __launch_bounds__(256) void prep_kernel(
    const float* __restrict__ WQ, const float* __restrict__ WK,
    const float* __restrict__ WV, const float* __restrict__ Wout,
    const float* __restrict__ head_weights, const int* __restrict__ active_heads_p,
    unsigned short* __restrict__ Mtr, unsigned short* __restrict__ Pbf,
    uint4v* __restrict__ zbase)
{
    int o = blockIdx.x * blockDim.x + threadIdx.x;
    if (o < 4096) {
        int d = o >> 6, a = o & 63;                       // Mtr[d][a] = M[a][d]
        float acc = 0.f;
        for (int j = 0; j < 64; ++j) acc += WQ[j*64 + a] * WK[j*64 + d];
        Mtr[o] = f2bf(acc * 0.125f);
    } else if (o < 8192) {
        int ah = active_heads_p[0];
        float hw = 0.f;
        for (int i = 0; i < ah; ++i) hw += head_weights[i];
        hw /= (float)ah;
        int o2 = o - 4096;
        int j = o2 >> 6, b = o2 & 63;                     // Pbf[j][b]
        float acc = 0.f;
        for (int d = 0; d < 64; ++d) acc += Wout[j*64 + d] * WV[d*64 + b];
        Pbf[o2] = f2bf(acc * hw);
    }
    // grid-stride zero of accum_bf + countv (contiguous, 16B-multiple)
    uint4v z = {0u, 0u, 0u, 0u};
    for (int j = o; j < ZU4; j += 262144) zbase[j] = z;
}

// Full per-cluster compute (R12-exact): GEMM1 -> GEMM2 -> softmax ->
// (E-half | GEMM3)x2 -> [optional next-cluster X park] -> atomic scatter.
template<bool WN>
__device__ __forceinline__ void cluster_compute(
    unsigned short* X, unsigned short* E,
    const int* ids, const float* biascl,
    const unsigned short* __restrict__ Mtr,
    unsigned short* __restrict__ accum_bf,
    int lane, int w, int m, int hk, int r, int cb,
    short8 nx0, short8 nx1, short8 nx2, short8 nx3)
{
    // ---- GEMM1: Z = X @ M  (m-tile w, K=64; M frags from global/L1) ----
    {
        floatx16 z0 = {}, z1 = {};
        #pragma unroll
        for (int ks = 0; ks < 4; ++ks) {
            short8 mb0 = *(const short8*)(Mtr + m * 64 + ks * 16 + hk);
            short8 mb1 = *(const short8*)(Mtr + (32 + m) * 64 + ks * 16 + hk);
            short8 a = *(const short8*)&X[(w * 32 + m) * XS + ks * 16 + hk];
            z0 = __builtin_amdgcn_mfma_f32_32x32x16_bf16(a, mb0, z0, 0, 0, 0);
            z1 = __builtin_amdgcn_mfma_f32_32x32x16_bf16(a, mb1, z1, 0, 0, 0);
        }
        #pragma unroll
        for (int rr = 0; rr < 16; ++rr) {   // wave-local rows 32w..32w+31
            int row = w * 32 + crow(rr, lane);
            E[row * XS + m]      = f2bf(z0[rr]);
            E[row * XS + 32 + m] = f2bf(z1[rr]);
        }
    }

    // ---- GEMM2: scores = Z @ X^T  (m-tile w, n-tiles 0..3, K=64) ----
    floatx16 sc[4] = {{}, {}, {}, {}};
    #pragma unroll
    for (int ks = 0; ks < 4; ++ks) {
        short8 a = *(const short8*)&E[(w * 32 + m) * XS + ks * 16 + hk];
        #pragma unroll
        for (int nt = 0; nt < 4; ++nt) {
            short8 b = *(const short8*)&X[(nt * 32 + m) * XS + ks * 16 + hk];
            sc[nt] = __builtin_amdgcn_mfma_f32_32x32x16_bf16(a, b, sc[nt], 0, 0, 0);
        }
    }

    // ---- bias + leaky_relu + exp + rowsum(shfl) + normalize (all fp32) ----
    const float b2 = biascl[m], b3 = biascl[32 + m];
    #pragma unroll
    for (int rr = 0; rr < 16; ++rr) {
        float a0 = sc[0][rr], a1 = sc[1][rr], a2 = sc[2][rr] + b2, a3 = sc[3][rr] + b3;
        a0 = a0 > 0.f ? a0 : 0.2f * a0;
        a1 = a1 > 0.f ? a1 : 0.2f * a1;
        a2 = a2 > 0.f ? a2 : 0.2f * a2;
        a3 = a3 > 0.f ? a3 : 0.2f * a3;
        a0 = __expf(a0); a1 = __expf(a1); a2 = __expf(a2); a3 = __expf(a3);
        float s4 = (a0 + a1) + (a2 + a3);       // row's 32-col partial per lane
        #pragma unroll
        for (int off = 1; off < 32; off <<= 1) s4 += __shfl_xor(s4, off, 64);
        float inv = __builtin_amdgcn_rcpf(s4);  // full 128-col rowsum (half-wave)
        sc[0][rr] = a0 * inv; sc[1][rr] = a1 * inv;
        sc[2][rr] = a2 * inv; sc[3][rr] = a3 * inv;
    }

    // ---- E-half 1 (cols 0..63) over Z rows (wave-local; in-order DS) ----
    #pragma unroll
    for (int rr = 0; rr < 16; ++rr) {
        int row = w * 32 + crow(rr, lane);
        E[row * XS + m]      = f2bf(sc[0][rr]);
        E[row * XS + 32 + m] = f2bf(sc[1][rr]);
    }

    // ---- GEMM3 half 1: t = 0..63 (B cols via ds_read_u16 from X) ----
    floatx16 g0 = {}, g1 = {};
    #pragma unroll
    for (int ks = 0; ks < 4; ++ks) {
        short8 a = *(const short8*)&E[(w * 32 + m) * XS + ks * 16 + hk];
        short8 b0, b1;
        #pragma unroll
        for (int j = 0; j < 8; ++j) {
            int t = ks * 16 + hk + j;
            b0[j] = (short)X[t * XS + m];
            b1[j] = (short)X[t * XS + 32 + m];
        }
        g0 = __builtin_amdgcn_mfma_f32_32x32x16_bf16(a, b0, g0, 0, 0, 0);
        g1 = __builtin_amdgcn_mfma_f32_32x32x16_bf16(a, b1, g1, 0, 0, 0);
    }

    // ---- E-half 2 (cols 64..127) ----
    #pragma unroll
    for (int rr = 0; rr < 16; ++rr) {
        int row = w * 32 + crow(rr, lane);
        E[row * XS + m]      = f2bf(sc[2][rr]);
        E[row * XS + 32 + m] = f2bf(sc[3][rr]);
    }

    // ---- GEMM3 half 2: t = 64..127 ----
    #pragma unroll
    for (int ks = 0; ks < 4; ++ks) {
        short8 a = *(const short8*)&E[(w * 32 + m) * XS + ks * 16 + hk];
        short8 b0, b1;
        #pragma unroll
        for (int j = 0; j < 8; ++j) {
            int t = 64 + ks * 16 + hk + j;
            b0[j] = (short)X[t * XS + m];
            b1[j] = (short)X[t * XS + 32 + m];
        }
        g0 = __builtin_amdgcn_mfma_f32_32x32x16_bf16(a, b0, g0, 0, 0, 0);
        g1 = __builtin_amdgcn_mfma_f32_32x32x16_bf16(a, b1, g1, 0, 0, 0);
    }

    // ---- park next cluster's X rows into E (wave-local rows; DS in-order
    //      guarantees these land after this wave's last E A-reads above) ----
    if (WN) {
        *(short8*)&E[r * XS + cb +  0] = nx0;
        *(short8*)&E[r * XS + cb +  8] = nx1;
        *(short8*)&E[r * XS + cb + 16] = nx2;
        *(short8*)&E[r * XS + cb + 24] = nx3;
    }

    // ---- pack adjacent cols (shfl_xor 1) + pk_add_bf16 scatter ----
    const bool ev = !(lane & 1);
    const int colbase = ev ? m : (31 + m);
    #pragma unroll
    for (int rr = 0; rr < 16; ++rr) {
        int row = w * 32 + crow(rr, lane);
        int nid = ids[row];
        float a0 = g0[rr], a1 = g1[rr];
        float t0 = __shfl_xor(a0, 1, 64);
        float t1 = __shfl_xor(a1, 1, 64);
        float lo = ev ? a0 : t1;
        float hi = ev ? t0 : a1;
        unsigned pk = (unsigned)f2bf(lo) | ((unsigned)f2bf(hi) << 16);
        unsigned long long addr =
            (unsigned long long)(accum_bf + (size_t)nid * 64 + colbase);
        asm volatile("global_atomic_pk_add_bf16 %0, %1, off"
                     :: "v"(addr), "v"(pk) : "memory");
    }
}

__global__ __launch_bounds__(256, 4) void attn_kernel(
    const float* __restrict__ x_var, const float* __restrict__ x_clause,
    const int* __restrict__ cvar, const int* __restrict__ ccl,
    const float* __restrict__ sat, const unsigned short* __restrict__ Mtr,
    unsigned short* __restrict__ accum_bf, float* __restrict__ countv)
{
    __shared__ unsigned short bufA[128 * XS];  // 18432
    __shared__ unsigned short bufB[128 * XS];  // 18432
    __shared__ int   ids0[128], ids1[128];     // 1024
    __shared__ float bias0[64], bias1[64];     // 512
    // total 38400 B -> 4 blocks/CU

    const int tid = threadIdx.x, lane = tid & 63, w = tid >> 6;
    const int m = lane & 31, hk = (lane >> 5) * 8;
    const int c0 = blockIdx.x * 2;             // this block owns c0, c0+1
    const int r = tid >> 1, half = tid & 1, cb = half * 32;

    // ---- ids for BOTH clusters (issued together -> one latency) ----
    int nid0, nid1;
    const float *src0, *src1;
    float sv0 = 0.f, sv1 = 0.f;
    if (r < 64) {
        nid0 = cvar[c0 * 64 + r];
        nid1 = cvar[c0 * 64 + 64 + r];         // cluster c0+1
        src0 = x_var + (size_t)nid0 * 64;
        src1 = x_var + (size_t)nid1 * 64;
    } else {
        int cid0 = ccl[c0 * 64 + (r - 64)];
        int cid1 = ccl[c0 * 64 + r];           // cluster c0+1
        nid0 = NV + cid0; nid1 = NV + cid1;
        src0 = x_clause + (size_t)cid0 * 64;
        src1 = x_clause + (size_t)cid1 * 64;
        if (half) { sv0 = sat[cid0]; sv1 = sat[cid1]; }
    }

    // ---- issue ALL 16 row loads (both clusters) back-to-back ----
    const float4* s40 = (const float4*)src0 + half * 8;
    const float4* s41 = (const float4*)src1 + half * 8;
    float4 v0[8], v1[8];
    #pragma unroll
    for (int i = 0; i < 8; ++i) v0[i] = s40[i];
    #pragma unroll
    for (int i = 0; i < 8; ++i) v1[i] = s41[i];

    if (!half) { ids0[r] = nid0; ids1[r] = nid1; }   // counts issued at END
    if (r >= 64 && half) { bias0[r - 64] = sv0; bias1[r - 64] = sv1; }

    // ---- c0 -> bufA (row-major bf16) ----
    {
        union { unsigned u[16]; short8 v[4]; } h0;
        #pragma unroll
        for (int i = 0; i < 8; ++i) {
            h0.u[2*i]   = pack2bf(v0[i].x, v0[i].y);
            h0.u[2*i+1] = pack2bf(v0[i].z, v0[i].w);
        }
        #pragma unroll
        for (int i = 0; i < 4; ++i) *(short8*)&bufA[r * XS + cb + i * 8] = h0.v[i];
    }
    // ---- c1 -> 16 packed VGPRs (held across c0 compute) ----
    union { unsigned u[16]; short8 v[4]; } h1;
    #pragma unroll
    for (int i = 0; i < 8; ++i) {
        h1.u[2*i]   = pack2bf(v1[i].x, v1[i].y);
        h1.u[2*i+1] = pack2bf(v1[i].z, v1[i].w);
    }

    bar_lds();   // bufA + ids visible

    // compute c0: X=bufA, scratch=bufB; park c1 rows into bufB near the end
    cluster_compute<true>(bufA, bufB, ids0, bias0, Mtr, accum_bf,
                          lane, w, m, hk, r, cb,
                          h1.v[0], h1.v[1], h1.v[2], h1.v[3]);

    bar_lds();   // all waves done reading bufA/bufB(c0); c1 X now in bufB.
                 // c0's atomic scatter intentionally still in flight.

    // compute c1: X=bufB, scratch=bufA
    short8 zz = {};
    cluster_compute<false>(bufB, bufA, ids1, bias1, Mtr, accum_bf,
                           lane, w, m, hk, r, cb, zz, zz, zz, zz);

    // ---- countv atomics at the TAIL: join the fire-and-forget scatter
    //      drain instead of contending with the startup x-row gathers ----
    if (!half) {
        atomicAdd(&countv[nid0], 1.0f);
        atomicAdd(&countv[nid1], 1.0f);
    }
}

// finalize (R12-exact): MFMA @ P, then float4 LDS-transpose epilogue.
// T stride 68 f32: row base 272B (16B-aligned), b128 reads at bank floor.
__global__ __launch_bounds__(256, 4) void finalize_kernel(
    const float* __restrict__ x_var, const float* __restrict__ x_clause,
    const unsigned short* __restrict__ accum_bf, const float* __restrict__ countv,
    const unsigned short* __restrict__ Pbf, const float* __restrict__ bout,
    float* __restrict__ out)
{
    __shared__ float T[4][32][68];   // 34816B, one 32x64 tile per wave
    __shared__ float cnts[256];      //  1024B -> total 35840 -> 4 blocks/CU
    const int tid = threadIdx.x, lane = tid & 63, w = tid >> 6;
    const int base = blockIdx.x * 256;
    {
        int n = base + tid;
        cnts[tid] = (n < NN) ? countv[n] : 1.f;
    }
    __syncthreads();

    const int m = lane & 31, hk = (lane >> 5) * 8;
    short8 pb[2][4];                              // P fragments via L1
    #pragma unroll
    for (int nt = 0; nt < 2; ++nt)
        #pragma unroll
        for (int ks = 0; ks < 4; ++ks)
            pb[nt][ks] = *(const short8*)(Pbf + (nt * 32 + m) * 64 + ks * 16 + hk);
    const float bias0 = bout[m], bias1 = bout[32 + m];

    const int r2 = lane >> 1, cb2 = (lane & 1) * 32;   // phase-B mapping

    #pragma unroll
    for (int tm = 0; tm < 2; ++tm) {
        int mt = w * 2 + tm;                      // rows base+mt*32 ..
        const unsigned short* arow = accum_bf + (size_t)(base + mt * 32 + m) * 64;
        floatx16 c0 = {}, c1 = {};
        #pragma unroll
        for (int ks = 0; ks < 4; ++ks) {
            short8 a = *(const short8*)(arow + ks * 16 + hk);
            c0 = __builtin_amdgcn_mfma_f32_32x32x16_bf16(a, pb[0][ks], c0, 0, 0, 0);
            c1 = __builtin_amdgcn_mfma_f32_32x32x16_bf16(a, pb[1][ks], c1, 0, 0, 0);
        }
        // ---- phase A: stage (c*inv + bias) to wave-private T ----
        #pragma unroll
        for (int rr = 0; rr < 16; ++rr) {
            int lr32 = crow(rr, lane);            // 0..31 within tile
            float inv = 1.0f / fmaxf(cnts[mt * 32 + lr32], 1.0f);
            T[w][lr32][m]      = c0[rr] * inv + bias0;
            T[w][lr32][32 + m] = c1[rr] * inv + bias1;
        }
        // wave-local DS is in-order: reads below see this wave's writes.
        // ---- phase B: float4 x-add + out-store (2 rows per lane-pair) ----
        int n2 = base + mt * 32 + r2;
        if (n2 < NN) {
            const float* xr = (n2 < NV) ? (x_var + (size_t)n2 * 64)
                                        : (x_clause + (size_t)(n2 - NV) * 64);
            float* orow = out + (size_t)n2 * 64;
            #pragma unroll
            for (int j = 0; j < 8; ++j) {
                float4 t = *(const float4*)&T[w][r2][cb2 + 4 * j];
                float4 xv = *(const float4*)&xr[cb2 + 4 * j];
                float4 o;
                o.x = t.x + xv.x; o.y = t.y + xv.y;
                o.z = t.z + xv.z; o.w = t.w + xv.w;
                *(float4*)&orow[cb2 + 4 * j] = o;
            }
        }
    }
}

extern "C" void kernel_launch(void* const* d_in, const int* in_sizes, int n_in,
                              void* d_out, int out_size, void* d_ws, size_t ws_size,
                              hipStream_t stream)
{
    const float* x_var        = (const float*)d_in[0];
    const float* x_clause     = (const float*)d_in[1];
    const int*   cvar         = (const int*)d_in[4];
    const int*   ccl          = (const int*)d_in[5];
    const float* sat          = (const float*)d_in[6];
    const int*   active_heads = (const int*)d_in[7];
    const float* WQ           = (const float*)d_in[8];
    const float* WK           = (const float*)d_in[9];
    const float* WV           = (const float*)d_in[10];
    const float* head_weights = (const float*)d_in[11];
    const float* Wout         = (const float*)d_in[12];
    const float* bout         = (const float*)d_in[13];

    unsigned short* accum_bf = (unsigned short*)d_ws;          // NN*64 bf16
    float* countv = (float*)(accum_bf + (size_t)NN * 64);      // NN f32
    unsigned short* Mtr = (unsigned short*)(countv + NN);      // 4096 bf16
    unsigned short* Pbf = Mtr + 4096;                          // 4096 bf16

    // prep zeroes accum_bf+countv itself (26.4MB contiguous) -> no memset
    prep_kernel<<<1024, 256, 0, stream>>>(WQ, WK, WV, Wout, head_weights,
                                          active_heads, Mtr, Pbf,
                                          (uint4v*)d_ws);
    attn_kernel<<<NCLUST / 2, 256, 0, stream>>>(
        x_var, x_clause, cvar, ccl, sat, Mtr, accum_bf, countv);
    finalize_kernel<<<(NN + 255) / 256, 256, 0, stream>>>(
        x_var, x_clause, accum_bf, countv, Pbf, bout, (float*)d_out);
}